// Round 4
// baseline (122.357 us; speedup 1.0000x reference)
//
#include <hip/hip_runtime.h>

// Problem constants
#define NB   4096   // B
#define ND   256    // D
#define N2B  8192   // 2B
#define INV_T 2.0f  // 1/TEMP, TEMP=0.5
#define NBD  128    // 8192 / 64  row-bands (64-row bands)
#define NSLOT 128   // P slots per row (write-once invariant)
#define NTILE 8256  // 128*129/2 triangular band pairs (= 8 XCDs * 1032)

typedef __attribute__((ext_vector_type(8))) short bf16x8;
typedef __attribute__((ext_vector_type(4))) float f32x4;

__device__ __forceinline__ void gload_lds16(const void* g, void* l) {
  __builtin_amdgcn_global_load_lds(
      (const __attribute__((address_space(1))) void*)g,
      (__attribute__((address_space(3))) void*)l, 16, 0, 0);
}

// fp32 -> bf16 (RNE) as raw bits
__device__ __forceinline__ unsigned short f2b(float f) {
  unsigned int u = __float_as_uint(f);
  u = (u + 0x7fffu + ((u >> 16) & 1u)) >> 16;
  return (unsigned short)u;
}
__device__ __forceinline__ float b2f(unsigned short h) {
  return __uint_as_float(((unsigned int)h) << 16);
}

// Kernel A: L2-normalize rows of [x_i; x_j] -> Z (bf16 bits).
//   diagE[zrow] = exp(diag/T)   (self term, subtracted in k_final)
//   pos[r] = dot(z_i[r], z_j[r]) (LDS exchange between i- and j-waves)
// Block 0 zero-inits lossAcc and ticket.
__global__ __launch_bounds__(256) void k_normalize(
    const float* __restrict__ xi, const float* __restrict__ xj,
    unsigned short* __restrict__ Z, float* __restrict__ diagE,
    float* __restrict__ pos, float* __restrict__ lossAcc,
    unsigned int* __restrict__ ticket) {
  __shared__ float sh[2][256];
  if (blockIdx.x == 0 && threadIdx.x == 0) { *lossAcc = 0.0f; *ticket = 0u; }
  int wave = threadIdx.x >> 6, lane = threadIdx.x & 63;
  int r = (int)blockIdx.x * 2 + (wave & 1);  // row in [0, NB)
  bool isJ = wave >= 2;
  const float* src = (isJ ? xj : xi) + (size_t)r * ND;
  int zrow = r + (isJ ? NB : 0);

  float4 v = *(const float4*)(src + lane * 4);
  float ss = v.x * v.x + v.y * v.y + v.z * v.z + v.w * v.w;
#pragma unroll
  for (int m = 1; m < 64; m <<= 1) ss += __shfl_xor(ss, m, 64);
  float scale = 1.0f / fmaxf(sqrtf(ss), 1e-12f);
  unsigned short h0 = f2b(v.x * scale), h1 = f2b(v.y * scale);
  unsigned short h2 = f2b(v.z * scale), h3 = f2b(v.w * scale);
  ushort4 st; st.x = h0; st.y = h1; st.z = h2; st.w = h3;
  *(ushort4*)(Z + (size_t)zrow * ND + lane * 4) = st;

  float f0 = b2f(h0), f1 = b2f(h1), f2 = b2f(h2), f3 = b2f(h3);
  float d = f0 * f0 + f1 * f1 + f2 * f2 + f3 * f3;
#pragma unroll
  for (int m = 1; m < 64; m <<= 1) d += __shfl_xor(d, m, 64);
  if (lane == 0) diagE[zrow] = __expf(d * INV_T);

  if (isJ) {
    float* s = sh[wave & 1] + lane * 4;
    s[0] = f0; s[1] = f1; s[2] = f2; s[3] = f3;
  }
  __syncthreads();
  if (!isJ) {
    const float* s = sh[wave] + lane * 4;
    float p = f0 * s[0] + f1 * s[1] + f2 * s[2] + f3 * s[3];
#pragma unroll
    for (int m = 1; m < 64; m <<= 1) p += __shfl_xor(p, m, 64);
    if (lane == 0) pos[r] = p;
  }
}

// Kernel B: SYMMETRIC triangular band GEMM + fused exp / dual reduction.
// ROUND-4 CHANGE: the limiter is per-BLOCK serial chains (stage->drain->
// barrier->compute->reduce), with only 2 chains/CU resident (64 KiB LDS).
// Round 3 doubled waves/block with ZERO effect (44.7->44.8 us) because
// waves share the block's barrier chain. Now: quarter the block.
//   - 64-row bands (NBD=128), triangular tiles (i<=j): 8256 blocks
//   - 256 threads (4 waves x 16 A-rows), Bs = 64x256 bf16 = 32 KiB
//   - 5 blocks/CU (launch_bounds(256,5)) -> 5 independent chains/CU
// Slot invariant: row r in band i receives row-partials at slots j in
// [i,128) from tiles (i,j), and transpose col-credits at slots i' in [0,i)
// from tiles (i',band(r)). Exactly NSLOT=128 slots/row, each written once
// -> no atomics, no zero-init; k_final sums all 128.
// Diagonal tiles (i==j) compute their full 64x64 directly (lower half is a
// legitimate row-sum contribution), and write no col-credit.
// Supertile scheduling kept: 16x16-band supertiles (8 diag x136 + 28
// off-diag x256 = 8256), XCD-contiguous (8256 = 8*1032, bijective) -> live
// Z window ~1 MiB per XCD -> L2-resident (round 2 verified: FETCH 10 MB).
__global__ __launch_bounds__(256, 5) void k_sym(
    const unsigned short* __restrict__ Z, float* __restrict__ P) {
  __shared__ alignas(16) unsigned short Bs[64 * ND];  // 32 KiB

  int tid = threadIdx.x;
  int wave = tid >> 6, lane = tid & 63;
  int quad = lane >> 4, c16 = lane & 15;

  // ---- supertile-major tile index, XCD-contiguous ----
  int g = ((int)blockIdx.x & 7) * (NTILE / 8) + ((int)blockIdx.x >> 3);
  int SI = 0, SJ = 0, u = g;
  bool found = false;
  for (int a = 0; a < 8 && !found; ++a) {
    for (int b = a; b < 8; ++b) {
      int sz = (a == b) ? 136 : 256;
      if (u < sz) { SI = a; SJ = b; found = true; break; }
      u -= sz;
    }
  }
  int ti, tj;
  if (SI == SJ) {  // triangular decode: 0 <= ti <= tj < 16
    ti = 0;
    while (u >= 16 - ti) { u -= 16 - ti; ++ti; }
    tj = ti + u;
  } else {
    ti = u >> 4; tj = u & 15;
  }
  int I = SI * 16 + ti, J = SJ * 16 + tj;  // 64-row band indices, I <= J
  bool diag = (I == J);

  int rowA = I * 64, rowB = J * 64;

  // Stage B-band (64 rows x K=256 bf16) -> LDS. Row = 32 chunks of 16B;
  // global chunk gc lands in slot gc ^ (row&31) (involution; read side
  // applies the same XOR). Wave-uniform LDS base, lane-swizzled src.
  int lr1 = lane >> 5, cs = lane & 31;
#pragma unroll
  for (int j = 0; j < 8; ++j) {
    int r0 = wave * 16 + j * 2;  // wave-uniform base row (2 rows / call)
    int row = r0 + lr1;
    int gc = cs ^ (row & 31);
    gload_lds16(Z + (size_t)(rowB + row) * ND + gc * 8, &Bs[r0 * ND]);
  }

  // A fragments in registers: wave owns 16 rows rowA + wave*16 .. +15
  bf16x8 afr[8];
  int wrow = rowA + wave * 16;
#pragma unroll
  for (int kk = 0; kk < 8; ++kk)
    afr[kk] = *(const bf16x8*)(Z + (size_t)(wrow + c16) * ND + kk * 32 +
                               quad * 8);

  asm volatile("s_waitcnt vmcnt(0)" ::: "memory");
  __syncthreads();

  // 32 MFMA per wave over the 16x64 output sub-tile
  f32x4 acc[4] = {};
  __builtin_amdgcn_s_setprio(1);
#pragma unroll
  for (int kk = 0; kk < 8; ++kk) {
    bf16x8 bfr[4];
#pragma unroll
    for (int ni = 0; ni < 4; ++ni) {
      int row = ni * 16 + c16;
      int slot = (kk * 4 + quad) ^ (row & 31);
      bfr[ni] = *(const bf16x8*)&Bs[row * ND + slot * 8];
    }
#pragma unroll
    for (int ni = 0; ni < 4; ++ni)
      acc[ni] = __builtin_amdgcn_mfma_f32_16x16x32_bf16(afr[kk], bfr[ni],
                                                        acc[ni], 0, 0, 0);
  }
  __builtin_amdgcn_s_setprio(0);

  // fused exp; row partials (over this tile's 64 cols) and col partials
  // (over its 64 rows). C/D: out_row = quad*4 + r, out_col = ni*16 + c16.
  float rs[4] = {0.0f, 0.0f, 0.0f, 0.0f};
  float csum[4] = {0.0f, 0.0f, 0.0f, 0.0f};

#pragma unroll
  for (int ni = 0; ni < 4; ++ni)
#pragma unroll
    for (int r = 0; r < 4; ++r) {
      float e = __expf(acc[ni][r] * INV_T);
      rs[r] += e;
      csum[ni] += e;
    }

  // row partials: reduce across c16 (the 16 cols of each frag)
#pragma unroll
  for (int m = 1; m <= 8; m <<= 1)
#pragma unroll
    for (int r = 0; r < 4; ++r) rs[r] += __shfl_xor(rs[r], m, 64);

#pragma unroll
  for (int r = 0; r < 4; ++r)
    if (c16 == r) {
      int row = wrow + quad * 4 + r;
      P[(size_t)row * NSLOT + J] = rs[r];
    }

  if (!diag) {
    // col partials: reduce across quad (the 16 rows of the wave's frags)
#pragma unroll
    for (int ni = 0; ni < 4; ++ni) {
      csum[ni] += __shfl_xor(csum[ni], 16, 64);
      csum[ni] += __shfl_xor(csum[ni], 32, 64);
    }
    __syncthreads();  // all waves done reading Bs -> safe to reuse as colred
    float* colred = (float*)Bs;  // [4][64]
    if (lane < 16) {
#pragma unroll
      for (int ni = 0; ni < 4; ++ni)
        colred[wave * 64 + ni * 16 + lane] = csum[ni];
    }
    __syncthreads();
    if (tid < 64) {
      float v = colred[tid] + colred[64 + tid] + colred[128 + tid] +
                colred[192 + tid];
      P[(size_t)(rowB + tid) * NSLOT + I] = v;
    }
  }
}

// Kernel C: 32 blocks x 256 rows. rowsum[r] = sum_{q<128} P[r][q] - diagE[r];
// term = log(rowsum) - pos[r%B]/T. Block-reduce -> one atomicAdd per block;
// ticketed last block writes out = lossAcc / 2B.
__global__ __launch_bounds__(256) void k_final(
    const float* __restrict__ P, const float* __restrict__ diagE,
    const float* __restrict__ pos, float* __restrict__ lossAcc,
    unsigned int* __restrict__ ticket, float* __restrict__ out) {
  __shared__ float red[4];
  int tid = threadIdx.x;
  int wave = tid >> 6, lane = tid & 63;
  int row = (int)blockIdx.x * 256 + tid;

  const float4* Pr = (const float4*)(P + (size_t)row * NSLOT);
  float s = 0.0f;
#pragma unroll
  for (int q = 0; q < 32; ++q) {
    float4 a = Pr[q];
    s += (a.x + a.y) + (a.z + a.w);
  }
  s -= diagE[row];
  float term = __logf(s) - INV_T * pos[row & (NB - 1)];
#pragma unroll
  for (int m = 1; m < 64; m <<= 1) term += __shfl_xor(term, m, 64);
  if (lane == 0) red[wave] = term;
  __syncthreads();
  if (tid == 0) {
    float bs = red[0] + red[1] + red[2] + red[3];
    atomicAdd(lossAcc, bs);
    __threadfence();
    unsigned int old = atomicAdd(ticket, 1u);
    if (old == 31u) {
      float v = atomicAdd(lossAcc, 0.0f);  // atomic read after all adds
      out[0] = v * (1.0f / (float)N2B);
    }
  }
}

extern "C" void kernel_launch(void* const* d_in, const int* in_sizes, int n_in,
                              void* d_out, int out_size, void* d_ws,
                              size_t ws_size, hipStream_t stream) {
  const float* xi = (const float*)d_in[0];
  const float* xj = (const float*)d_in[1];
  float* out = (float*)d_out;
  char* ws = (char*)d_ws;
  unsigned short* Z = (unsigned short*)ws;           // 4 MiB
  float* P = (float*)(ws + (4u << 20));              // 8192*128*4 = 4 MiB
  float* pos = (float*)(ws + (8u << 20));            // 16 KiB
  float* diagE = (float*)(ws + (8u << 20) + 65536);  // 32 KiB
  float* lossAcc = (float*)(ws + (8u << 20) + 131072);
  unsigned int* ticket = (unsigned int*)(ws + (8u << 20) + 131072 + 64);

  k_normalize<<<dim3(NB / 2), dim3(256), 0, stream>>>(xi, xj, Z, diagE, pos,
                                                      lossAcc, ticket);
  k_sym<<<dim3(NTILE), dim3(256), 0, stream>>>(Z, P);
  k_final<<<dim3(32), dim3(256), 0, stream>>>(P, diagE, pos, lossAcc, ticket,
                                              out);
}

// Round 5
// 104.549 us; speedup vs baseline: 1.1703x; 1.1703x over previous
//
#include <hip/hip_runtime.h>

// Problem constants
#define NB   4096   // B
#define ND   256    // D
#define N2B  8192   // 2B
#define INV_T 2.0f  // 1/TEMP, TEMP=0.5
#define NBAND 64    // 128-row bands
#define NBLK  544   // sum_I ceil((64-I)/4) = 8 XCDs * 68

typedef __attribute__((ext_vector_type(8))) short bf16x8;
typedef __attribute__((ext_vector_type(4))) float f32x4;

__device__ __forceinline__ void gload_lds16(const void* g, void* l) {
  __builtin_amdgcn_global_load_lds(
      (const __attribute__((address_space(1))) void*)g,
      (__attribute__((address_space(3))) void*)l, 16, 0, 0);
}

// fp32 -> bf16 (RNE) as raw bits
__device__ __forceinline__ unsigned short f2b(float f) {
  unsigned int u = __float_as_uint(f);
  u = (u + 0x7fffu + ((u >> 16) & 1u)) >> 16;
  return (unsigned short)u;
}
__device__ __forceinline__ float b2f(unsigned short h) {
  return __uint_as_float(((unsigned int)h) << 16);
}

// Kernel A: L2-normalize rows of [x_i; x_j] -> Z (bf16 bits).
__global__ __launch_bounds__(256) void k_normalize(
    const float* __restrict__ xi, const float* __restrict__ xj,
    unsigned short* __restrict__ Z, float* __restrict__ diagE,
    float* __restrict__ pos, float* __restrict__ lossAcc,
    unsigned int* __restrict__ ticket) {
  __shared__ float sh[2][256];
  if (blockIdx.x == 0 && threadIdx.x == 0) { *lossAcc = 0.0f; *ticket = 0u; }
  int wave = threadIdx.x >> 6, lane = threadIdx.x & 63;
  int r = (int)blockIdx.x * 2 + (wave & 1);  // row in [0, NB)
  bool isJ = wave >= 2;
  const float* src = (isJ ? xj : xi) + (size_t)r * ND;
  int zrow = r + (isJ ? NB : 0);

  float4 v = *(const float4*)(src + lane * 4);
  float ss = v.x * v.x + v.y * v.y + v.z * v.z + v.w * v.w;
#pragma unroll
  for (int m = 1; m < 64; m <<= 1) ss += __shfl_xor(ss, m, 64);
  float scale = 1.0f / fmaxf(sqrtf(ss), 1e-12f);
  unsigned short h0 = f2b(v.x * scale), h1 = f2b(v.y * scale);
  unsigned short h2 = f2b(v.z * scale), h3 = f2b(v.w * scale);
  ushort4 st; st.x = h0; st.y = h1; st.z = h2; st.w = h3;
  *(ushort4*)(Z + (size_t)zrow * ND + lane * 4) = st;

  float f0 = b2f(h0), f1 = b2f(h1), f2 = b2f(h2), f3 = b2f(h3);
  float d = f0 * f0 + f1 * f1 + f2 * f2 + f3 * f3;
#pragma unroll
  for (int m = 1; m < 64; m <<= 1) d += __shfl_xor(d, m, 64);
  if (lane == 0) diagE[zrow] = __expf(d * INV_T);

  if (isJ) {
    float* s = sh[wave & 1] + lane * 4;
    s[0] = f0; s[1] = f1; s[2] = f2; s[3] = f3;
  }
  __syncthreads();
  if (!isJ) {
    const float* s = sh[wave] + lane * 4;
    float p = f0 * s[0] + f1 * s[1] + f2 * s[2] + f3 * s[3];
#pragma unroll
    for (int m = 1; m < 64; m <<= 1) p += __shfl_xor(p, m, 64);
    if (lane == 0) pos[r] = p;
  }
}

// Kernel B: symmetric triangular GEMM, PIPELINED streaming form.
// ROUND-5: two fixes from the round-4 post-mortem.
//  (1) A over-fetch: A-frags were per-lane 16B @ stride-512 = 4x line
//      over-fetch (~400 MB of the ~530 MB moved). Now A-band is staged
//      COALESCED into LDS (verified chunk-swizzle), frags bounced to regs,
//      then the same 64 KiB LDS is reused as the B double-buffer.
//  (2) Phase-locking: every prior variant was one stage->vmcnt(0)->barrier->
//      compute phase per block; resident blocks phase-lock so memory and
//      compute burst alternately device-wide. Now each block streams up to
//      8 x (128row x 64col) tiles through a 2x32 KiB double buffer:
//      STAGE(t+1) issued BEFORE compute(t); one vmcnt(0)+barrier per tile
//      (T3-lite: loads get a full compute phase to land).
// Block (I,k): A-band I (128 rows), bands J in [I+4k, I+4k+nb), nb<=4,
// as nt=2*nb 64-col tiles. 544 blocks (8*68, XCD-bijective), 512 thr,
// 68 KiB LDS -> 2 blocks/CU. Write-once P: row-partials accumulated over
// each band's 2 tiles (unique block per band-pair); col-credits per tile
// via double-buffered colred (diag band skips credit).
__global__ __launch_bounds__(512, 4) void k_sym(
    const unsigned short* __restrict__ Z, float* __restrict__ P) {
  __shared__ alignas(16) unsigned short ldsU[32768];  // 64 KiB: A, then B dbuf
  __shared__ float colred[2][8][64];                  // 4 KiB, dbuf'd per tile

  int tid = threadIdx.x;
  int wave = tid >> 6, lane = tid & 63;
  int quad = lane >> 4, c16 = lane & 15;
  int lr1 = lane >> 5, cs = lane & 31;

  // XCD-bijective remap, then decode g -> (I, k)
  int g = ((int)blockIdx.x & 7) * (NBLK / 8) + ((int)blockIdx.x >> 3);
  int I = 0, acc0 = 0;
  while (acc0 + ((64 - I + 3) >> 2) <= g) { acc0 += (64 - I + 3) >> 2; ++I; }
  int k = g - acc0;
  int b0 = I + 4 * k;                 // first J band (b0 >= I)
  int nb = min(4, 64 - b0);           // bands this block
  int nt = nb * 2;                    // 64-col tiles
  int q0 = b0 * 2;                    // first 64-col chunk
  int rowA = I * 128;

  // ---- prologue: stage A-band (128 x 512B) coalesced -> full 64 KiB ----
#pragma unroll
  for (int j = 0; j < 8; ++j) {
    int r0 = wave * 16 + j * 2;       // wave-uniform base (2 rows / call)
    int row = r0 + lr1;
    int gc = cs ^ (row & 31);
    gload_lds16(Z + (size_t)(rowA + row) * ND + gc * 8, &ldsU[r0 * ND]);
  }
  asm volatile("s_waitcnt vmcnt(0)" ::: "memory");
  __syncthreads();

  // A fragments LDS -> regs (same swizzle on read side)
  bf16x8 afr[8];
  {
    int arow = wave * 16 + c16;
    const unsigned short* ap = &ldsU[arow * ND];
    int ax = arow & 31;
#pragma unroll
    for (int kk = 0; kk < 8; ++kk)
      afr[kk] = *(const bf16x8*)&ap[((kk * 4 + quad) ^ ax) * 8];
  }
  asm volatile("s_waitcnt lgkmcnt(0)" ::: "memory");
  __syncthreads();  // all afr read -> LDS free for B buffers

  // B tile stager: tile t (64 Z-rows x 512B = 32 KiB) -> half h
  auto STAGE = [&](int t, int h) {
    int base = (q0 + t) * 64;
#pragma unroll
    for (int j = 0; j < 4; ++j) {
      int r0 = wave * 8 + j * 2;      // wave-uniform base
      int row = r0 + lr1;
      int gc = cs ^ (row & 31);
      gload_lds16(Z + (size_t)(base + row) * ND + gc * 8,
                  &ldsU[h * 16384 + r0 * ND]);
    }
  };

  STAGE(0, 0);
  asm volatile("s_waitcnt vmcnt(0)" ::: "memory");
  __syncthreads();

  int wrow = rowA + wave * 16;
  float rs[4] = {0.0f, 0.0f, 0.0f, 0.0f};

  for (int t = 0; t < nt; ++t) {
    int h = t & 1;
    if (t + 1 < nt) STAGE(t + 1, h ^ 1);  // in flight across this phase

    // compute tile t: 32 MFMA/wave (16 A-rows x 64 cols)
    f32x4 acc[4] = {};
    __builtin_amdgcn_s_setprio(1);
#pragma unroll
    for (int kk = 0; kk < 8; ++kk) {
      bf16x8 bfr[4];
#pragma unroll
      for (int ni = 0; ni < 4; ++ni) {
        int row = ni * 16 + c16;
        int slot = (kk * 4 + quad) ^ (row & 31);
        bfr[ni] = *(const bf16x8*)&ldsU[h * 16384 + row * ND + slot * 8];
      }
#pragma unroll
      for (int ni = 0; ni < 4; ++ni)
        acc[ni] = __builtin_amdgcn_mfma_f32_16x16x32_bf16(afr[kk], bfr[ni],
                                                          acc[ni], 0, 0, 0);
    }
    __builtin_amdgcn_s_setprio(0);

    // fused exp epilogue; C/D: out_row = quad*4+r, out_col = ni*16+c16
    float cs_[4] = {0.0f, 0.0f, 0.0f, 0.0f};
#pragma unroll
    for (int ni = 0; ni < 4; ++ni)
#pragma unroll
      for (int r = 0; r < 4; ++r) {
        float e = __expf(acc[ni][r] * INV_T);
        rs[r] += e;
        cs_[ni] += e;
      }
    // col partial: sum this wave's 16 rows (quad groups)
#pragma unroll
    for (int ni = 0; ni < 4; ++ni) {
      cs_[ni] += __shfl_xor(cs_[ni], 16, 64);
      cs_[ni] += __shfl_xor(cs_[ni], 32, 64);
    }
    if (lane < 16) {
#pragma unroll
      for (int ni = 0; ni < 4; ++ni)
        colred[h][wave][ni * 16 + lane] = cs_[ni];
    }

    asm volatile("s_waitcnt vmcnt(0)" ::: "memory");  // drain STAGE(t+1)
    __syncthreads();

    // col-credit for tile t (cross-wave sum, written once per row)
    int Jt = b0 + (t >> 1);
    if (Jt != I && tid < 64) {
      float v = 0.0f;
#pragma unroll
      for (int w = 0; w < 8; ++w) v += colred[h][w][tid];
      P[(size_t)((q0 + t) * 64 + tid) * NBAND + I] = v;
    }
    // band row-partial write (after both tiles of band Jt)
    if (t & 1) {
      float r4[4] = {rs[0], rs[1], rs[2], rs[3]};
#pragma unroll
      for (int m = 1; m <= 8; m <<= 1)
#pragma unroll
        for (int r = 0; r < 4; ++r) r4[r] += __shfl_xor(r4[r], m, 64);
#pragma unroll
      for (int r = 0; r < 4; ++r)
        if (c16 == r)
          P[(size_t)(wrow + quad * 4 + r) * NBAND + Jt] = r4[r];
      rs[0] = rs[1] = rs[2] = rs[3] = 0.0f;
    }
  }
}

// Kernel C: 32 blocks x 256 rows. rowsum[r] = sum_{q<64} P[r][q] - diagE[r];
// term = log(rowsum) - pos[r%B]/T. Block-reduce -> one atomicAdd per block;
// ticketed last block writes out = lossAcc / 2B.
__global__ __launch_bounds__(256) void k_final(
    const float* __restrict__ P, const float* __restrict__ diagE,
    const float* __restrict__ pos, float* __restrict__ lossAcc,
    unsigned int* __restrict__ ticket, float* __restrict__ out) {
  __shared__ float red[4];
  int tid = threadIdx.x;
  int wave = tid >> 6, lane = tid & 63;
  int row = (int)blockIdx.x * 256 + tid;

  const float4* Pr = (const float4*)(P + (size_t)row * NBAND);
  float s = 0.0f;
#pragma unroll
  for (int q = 0; q < 16; ++q) {
    float4 a = Pr[q];
    s += (a.x + a.y) + (a.z + a.w);
  }
  s -= diagE[row];
  float term = __logf(s) - INV_T * pos[row & (NB - 1)];
#pragma unroll
  for (int m = 1; m < 64; m <<= 1) term += __shfl_xor(term, m, 64);
  if (lane == 0) red[wave] = term;
  __syncthreads();
  if (tid == 0) {
    float bs = red[0] + red[1] + red[2] + red[3];
    atomicAdd(lossAcc, bs);
    __threadfence();
    unsigned int old = atomicAdd(ticket, 1u);
    if (old == 31u) {
      float v = atomicAdd(lossAcc, 0.0f);  // atomic read after all adds
      out[0] = v * (1.0f / (float)N2B);
    }
  }
}

extern "C" void kernel_launch(void* const* d_in, const int* in_sizes, int n_in,
                              void* d_out, int out_size, void* d_ws,
                              size_t ws_size, hipStream_t stream) {
  const float* xi = (const float*)d_in[0];
  const float* xj = (const float*)d_in[1];
  float* out = (float*)d_out;
  char* ws = (char*)d_ws;
  unsigned short* Z = (unsigned short*)ws;           // 4 MiB
  float* P = (float*)(ws + (4u << 20));              // 8192*64*4 = 2 MiB
  float* pos = (float*)(ws + (6u << 20));            // 16 KiB
  float* diagE = (float*)(ws + (6u << 20) + 65536);  // 32 KiB
  float* lossAcc = (float*)(ws + (6u << 20) + 131072);
  unsigned int* ticket = (unsigned int*)(ws + (6u << 20) + 131072 + 64);

  k_normalize<<<dim3(NB / 2), dim3(256), 0, stream>>>(xi, xj, Z, diagE, pos,
                                                      lossAcc, ticket);
  k_sym<<<dim3(NBLK), dim3(512), 0, stream>>>(Z, P);
  k_final<<<dim3(32), dim3(256), 0, stream>>>(P, diagE, pos, lossAcc, ticket,
                                              out);
}